// Round 7
// baseline (205.748 us; speedup 1.0000x reference)
//
#include <hip/hip_runtime.h>
#include <stdint.h>
#include <math.h>

#define SLEN 2048
#define EPT 8
#define NTHREADS 256
#define TOKENS_PER_OUT 8388608   // 1024*4*2048

// ---------- Threefry-2x32, 20 rounds, matches jax._src.prng ----------
__host__ __device__ __forceinline__ void tf2x32(uint32_t k0, uint32_t k1,
                                                uint32_t x0, uint32_t x1,
                                                uint32_t &o0, uint32_t &o1) {
  uint32_t ks2 = 0x1BD11BDAu ^ k0 ^ k1;
  x0 += k0; x1 += k1;
#define TFR(r) { x0 += x1; x1 = (x1 << (r)) | (x1 >> (32 - (r))); x1 ^= x0; }
  TFR(13) TFR(15) TFR(26) TFR(6)
  x0 += k1;  x1 += ks2 + 1u;
  TFR(17) TFR(29) TFR(16) TFR(24)
  x0 += ks2; x1 += k0 + 2u;
  TFR(13) TFR(15) TFR(26) TFR(6)
  x0 += k0;  x1 += k1 + 3u;
  TFR(17) TFR(29) TFR(16) TFR(24)
  x0 += k1;  x1 += ks2 + 4u;
  TFR(13) TFR(15) TFR(26) TFR(6)
  x0 += ks2; x1 += k0 + 5u;
#undef TFR
  o0 = x0; o1 = x1;
}

__device__ __forceinline__ float u01_from_bits(uint32_t bits) {
  return __uint_as_float((bits >> 9) | 0x3F800000u) - 1.0f;
}

// Correctly-rounded-quality f32 log (verified bit-exact vs ref through R6).
// Only used for ~1-4 boundary candidates per row + once per row in erfinv.
__device__ __forceinline__ float log_cr(float x) {
#pragma clang fp contract(off)
  uint32_t xb   = __float_as_uint(x);
  uint32_t mant = xb & 0x7FFFFFu;
  int      e    = (int)(xb >> 23) - 127;
  bool     big  = mant > 0x3504F3u;              // m > sqrt(2)
  e += big ? 1 : 0;
  uint32_t hi = (big ? 0x3FE00000u : 0x3FF00000u) | (mant >> 3);
  double m = __longlong_as_double(((long long)hi << 32) | (long long)(mant << 29));
  double mp1 = m + 1.0;
  double y = __builtin_amdgcn_rcp(mp1);
  y = fma(fma(-mp1, y, 1.0), y, y);
  double r = (m - 1.0) * y;
  double t = r * r;
  double p = fma(0.07692307692307693, t, 0.09090909090909091);
  p = fma(p, t, 0.1111111111111111);
  p = fma(p, t, 0.14285714285714285);
  p = fma(p, t, 0.2);
  p = fma(p, t, 0.3333333333333333);
  p = fma(p, t, 1.0);
  return (float)fma((double)e, 0.6931471805599453, (r + r) * p);
}

// XLA ErfInv f32 expander (Giles poly), log1p per ElementalIrEmitter::EmitLog1p
__device__ float erfinv_xla(float x) {
#pragma clang fp contract(off)
  float x2  = x * x;
  float nx2 = -x2;
  float l1p;
  if (fabsf(nx2) < 1e-4f) {
    l1p = (-0.5f * nx2 + 1.0f) * nx2;
  } else {
    l1p = log_cr(1.0f + nx2);
  }
  float w = -l1p;
  float p;
  if (w < 5.0f) {
    float ww = w - 2.5f;
    p = 2.81022636e-08f;
    p = p * ww + 3.43273939e-07f;
    p = p * ww + -3.5233877e-06f;
    p = p * ww + -4.39150654e-06f;
    p = p * ww + 0.00021858087f;
    p = p * ww + -0.00125372503f;
    p = p * ww + -0.00417768164f;
    p = p * ww + 0.246640727f;
    p = p * ww + 1.50140941f;
  } else {
    float ww = sqrtf(w) - 3.0f;
    p = -0.000200214257f;
    p = p * ww + 0.000100950558f;
    p = p * ww + 0.00134934322f;
    p = p * ww + -0.00367342844f;
    p = p * ww + 0.00573950773f;
    p = p * ww + -0.0076224613f;
    p = p * ww + 0.00943887047f;
    p = p * ww + 1.00167406f;
    p = p * ww + 2.83297682f;
  }
  return p * x;
}

// order-preserving f32 -> uint32 map and inverse
__device__ __forceinline__ uint32_t mapf(float key) {
  uint32_t kb = __float_as_uint(key);
  return (kb & 0x80000000u) ? ~kb : (kb | 0x80000000u);
}
__device__ __forceinline__ float unmapf(uint32_t m) {
  uint32_t kb = (m & 0x80000000u) ? (m & 0x7FFFFFFFu) : ~m;
  return __uint_as_float(kb);
}

// exact key for one element (bit-exact XLA chain; candidates only)
__device__ __forceinline__ uint32_t exact_mapped_key(float w, uint32_t bits) {
#pragma clang fp contract(off)
  float f  = u01_from_bits(bits);
  float uu = fmaxf(1.17549435e-38f, f * 1.0f + 1.17549435e-38f);
  float g  = -log_cr(-log_cr(uu));
  float key = (w > 0.0f) ? (log_cr(fmaxf(w, 1e-30f)) + g) : -__builtin_inff();
  return mapf(key);
}

#define LN2F 0.69314718f

__global__ __launch_bounds__(NTHREADS, 6)
void gumbel_topk_mask(const float* __restrict__ wfull,   // (B,C,2S) f32
                      const int*   __restrict__ attn,    // (B,C,S) i32
                      const int*   __restrict__ ids,     // (B,C,S) i32
                      int* __restrict__ out,             // 3x(B,C,S) i32 concat
                      uint32_t kg0, uint32_t kg1, uint32_t kn0, uint32_t kn1) {
#pragma clang fp contract(off)
  const int row  = blockIdx.x;
  const int t    = threadIdx.x;
  const int lane = t & 63;

  __shared__ __align__(16) uint32_t hist[2][256];
  __shared__ uint32_t candKey[SLEN];
  __shared__ unsigned short candIdx[SLEN];
  __shared__ unsigned char  flags[SLEN];
  __shared__ int  asum_s, d_s, ncand_s;
  __shared__ uint32_t prefix_s, remaining_s;

  const size_t rbase = (size_t)row * SLEN;
  const size_t wbase = (size_t)row * (2 * SLEN);
  const int    base  = t * EPT;            // contiguous chunk per thread

  hist[0][t] = 0u;
  hist[1][t] = 0u;
  if (t == 0) { asum_s = 0; d_s = 0; ncand_s = 0; prefix_s = 0u; }

  // ---- phase 1: loads + APPROX keys via hardware v_log_f32 ----
  const float4* wv4 = (const float4*)(wfull + wbase + base);
  float4 w0 = wv4[0], w1 = wv4[1];
  const int4* av4 = (const int4*)(attn + rbase + base);
  int4 a0 = av4[0], a1 = av4[1];
  const int4* iv4 = (const int4*)(ids + rbase + base);
  int4 i0 = iv4[0], i1 = iv4[1];
  int psum = a0.x + a0.y + a0.z + a0.w + a1.x + a1.y + a1.z + a1.w;

  float wl[EPT] = {w0.x, w0.y, w0.z, w0.w, w1.x, w1.y, w1.z, w1.w};
  uint32_t mloc[EPT];
#pragma unroll
  for (int e = 0; e < EPT; ++e) {
    uint32_t o0, o1;
    tf2x32(kg0, kg1, 0u, (uint32_t)(rbase + base + e), o0, o1);
    float f  = u01_from_bits(o0 ^ o1);
    float uu = fmaxf(1.17549435e-38f, f * 1.0f + 1.17549435e-38f);
    float lu = __builtin_amdgcn_logf(uu) * LN2F;           // ~ln u
    float y  = fmaxf(-lu, 8.0e-8f);                        // -ln u > 0
    float g  = -(__builtin_amdgcn_logf(y) * LN2F);         // ~gumbel
    float lw = __builtin_amdgcn_logf(fmaxf(wl[e], 1e-30f)) * LN2F;
    float keyc = (wl[e] > 0.0f) ? (lw + g) : -__builtin_inff();
    mloc[e] = mapf(keyc);                // approx mapped key, |err| <= ~3e-5
  }

  // attention-sum: wave reduce now, atomic after barrier
#pragma unroll
  for (int off = 32; off; off >>= 1) psum += __shfl_down(psum, off, 64);
  __syncthreads();                       // zero-inits visible
  if (lane == 0) atomicAdd(&asum_s, psum);
#pragma unroll
  for (int e = 0; e < EPT; ++e) atomicAdd(&hist[0][mloc[e] >> 24], 1u);
  __syncthreads();                       // asum + pass-3 hist complete

  // ---- num_to_mask (uniform, all threads) ----
  int kk;
  {
    uint32_t o0, o1;
    tf2x32(kn0, kn1, 0u, (uint32_t)row, o0, o1);
    float f   = u01_from_bits(o0 ^ o1);
    float lo  = __uint_as_float(0xBF7FFFFFu);      // nextafter(-1,0)
    float u2  = fmaxf(lo, f * 2.0f + lo);          // (1-lo) rounds to 2.0f
    float z   = erfinv_xla(u2);
    float nrm = 1.4142135623730951f * z;
    float frac = 0.15f + 0.0375f * nrm;
    kk = (int)floorf((float)asum_s * frac);
  }

  // ---- radix-select k-th largest APPROX key (value only, 4 full passes) ----
  uint32_t candLoU, candHiU;
  if (kk <= 0)         { candHiU = 0xFFFFFFFFu; candLoU = 0xFFFFFFFFu; }  // none masked
  else if (kk >= SLEN) { candHiU = 0u;          candLoU = 1u; }           // all masked
  else {
    uint32_t need = (uint32_t)kk;
    int cur = 0;
    for (int p = 3; p >= 0; --p) {
      if (t < 64) {                        // wave 0: bin selection
        uint4 hq = ((const uint4*)hist[cur])[t];     // bins 4t..4t+3
        uint32_t hh[4] = {hq.x, hq.y, hq.z, hq.w};
        uint32_t gs  = hh[0] + hh[1] + hh[2] + hh[3];
        uint32_t sfx = gs;                           // inclusive suffix sum
#pragma unroll
        for (int off = 1; off < 64; off <<= 1) {
          uint32_t n = __shfl_down(sfx, off, 64);
          if (t + off < 64) sfx += n;
        }
        uint32_t SS[4];
        SS[3] = sfx - gs;                            // sum over lanes > t
        SS[2] = SS[3] + hh[3];
        SS[1] = SS[2] + hh[2];
        SS[0] = SS[1] + hh[1];
#pragma unroll
        for (int i = 0; i < 4; ++i) {
          if (hh[i] && SS[i] < need && need <= SS[i] + hh[i]) {  // unique winner
            prefix_s |= ((uint32_t)(4 * t + i)) << (8 * p);
            remaining_s = need - SS[i];
          }
        }
      } else {                             // other waves: clear next buffer
        int idx = t - 64;
        hist[cur ^ 1][idx] = 0u;
        if (idx < 64) hist[cur ^ 1][idx + 192] = 0u;
      }
      __syncthreads();
      need = remaining_s;
      if (p > 0) {
        uint32_t pref = prefix_s;
        int sh = 8 * p;
#pragma unroll
        for (int e = 0; e < EPT; ++e) {
          uint32_t m = mloc[e];
          if ((m >> sh) == (pref >> sh))
            atomicAdd(&hist[cur ^ 1][(m >> (sh - 8)) & 255u], 1u);
        }
      }
      cur ^= 1;
      __syncthreads();
    }
    float vT = unmapf(prefix_s);           // k-th largest approx key value
    candHiU = mapf(vT + 1.0e-3f);          // margin >> max approx error
    candLoU = mapf(vT - 1.0e-3f);
  }

  // ---- classify: definite above / definite below / candidate ----
  int dcnt = 0;
#pragma unroll
  for (int e = 0; e < EPT; ++e) {
    uint32_t m = mloc[e];
    if (m > candHiU) {
      ++dcnt;
    } else if (m >= candLoU) {
      int slot = atomicAdd(&ncand_s, 1);
      candIdx[slot] = (unsigned short)(base + e);
    }
  }
#pragma unroll
  for (int off = 32; off; off >>= 1) dcnt += __shfl_down(dcnt, off, 64);
  if (lane == 0) atomicAdd(&d_s, dcnt);
  __syncthreads();                         // list + D complete

  const int D = d_s, ncand = ncand_s;
  const int need2 = kk - D;                // candidates to mask

  // ---- exact keys for candidates (rare; bit-exact verified chain) ----
  for (int s = t; s < ncand; s += NTHREADS) {
    int pos = candIdx[s];
    float w = wfull[wbase + pos];
    uint32_t o0, o1;
    tf2x32(kg0, kg1, 0u, (uint32_t)(rbase + pos), o0, o1);
    candKey[s] = exact_mapped_key(w, o0 ^ o1);
  }
  __syncthreads();

  // ---- exact stable selection among candidates ----
  for (int s = t; s < ncand; s += NTHREADS) {
    uint32_t ki = candKey[s];
    int      pi = candIdx[s];
    int cnt = 0;
    for (int j = 0; j < ncand; ++j) {
      uint32_t kj = candKey[j];
      int      pj = candIdx[j];
      cnt += (kj > ki || (kj == ki && pj < pi)) ? 1 : 0;
    }
    flags[pi] = (cnt < need2) ? 1 : 0;
  }
  __syncthreads();

  // ---- epilogue ----
  int idv[EPT] = {i0.x, i0.y, i0.z, i0.w, i1.x, i1.y, i1.z, i1.w};
  int oid[EPT], omk[EPT], olb[EPT];
#pragma unroll
  for (int e = 0; e < EPT; ++e) {
    uint32_t m = mloc[e];
    bool msk = (m > candHiU) || (m >= candLoU && flags[base + e]);
    oid[e] = msk ? 103 : idv[e];      // MASK_ID
    omk[e] = msk ? 1 : 0;
    olb[e] = msk ? -1 : 0;
  }
  int4* po = (int4*)(out + rbase + base);
  po[0] = make_int4(oid[0], oid[1], oid[2], oid[3]);
  po[1] = make_int4(oid[4], oid[5], oid[6], oid[7]);
  int4* pm = (int4*)(out + TOKENS_PER_OUT + rbase + base);
  pm[0] = make_int4(omk[0], omk[1], omk[2], omk[3]);
  pm[1] = make_int4(omk[4], omk[5], omk[6], omk[7]);
  int4* pl = (int4*)(out + 2 * TOKENS_PER_OUT + rbase + base);
  pl[0] = make_int4(olb[0], olb[1], olb[2], olb[3]);
  pl[1] = make_int4(olb[4], olb[5], olb[6], olb[7]);
}

extern "C" void kernel_launch(void* const* d_in, const int* in_sizes, int n_in,
                              void* d_out, int out_size, void* d_ws, size_t ws_size,
                              hipStream_t stream) {
  (void)n_in; (void)d_ws; (void)ws_size; (void)out_size;
  const float* wfull = (const float*)d_in[0];   // my_attention_mask (B,C,2S)
  const int*   attn  = (const int*)d_in[1];     // attention_mask    (B,C,S)
  const int*   ids   = (const int*)d_in[2];     // input_ids         (B,C,S)
  int* out = (int*)d_out;

  // jax.random.key(42) -> (0,42); partitionable split: kg=enc(key,(0,0)), kn=enc(key,(0,1))
  uint32_t kg0, kg1, kn0, kn1, o0, o1;
  tf2x32(0u, 42u, 0u, 0u, o0, o1); kg0 = o0; kg1 = o1;
  tf2x32(0u, 42u, 0u, 1u, o0, o1); kn0 = o0; kn1 = o1;

  int rows = in_sizes[1] / SLEN;                // 4096
  hipLaunchKernelGGL(gumbel_topk_mask, dim3(rows), dim3(NTHREADS), 0, stream,
                     wfull, attn, ids, out, kg0, kg1, kn0, kn1);
}